// Round 5
// baseline (383.795 us; speedup 1.0000x reference)
//
#include <hip/hip_runtime.h>
#include <math.h>

#define TW 16                // tile width  (output cols)
#define TH 32                // tile height (output rows)
#define HR (TH + 10)         // 42 halo rows
#define SSTRIDE 29           // s1/s2 row stride: ODD -> octet bank parity alternates (conflict-free b32)
#define HSTRIDE 20           // hbuf col stride
#define SC1 0.0001f
#define SC2 0.0009f
#define PLANES 48
#define NSLOT 64

struct SmemT {
    float s1[HR][SSTRIDE];       // 4872 B
    float s2[HR][SSTRIDE];       // 4872 B
    float hbuf[5][HR][HSTRIDE];  // 16800 B
    float rbuf[8];
};                               // total 26576 B -> 6 blocks/CU

// ---------------- core: one 16x32 SSIM tile -------------------------------
__device__ __forceinline__ void ssim_tile(
        SmemT* sm,
        const float* __restrict__ p1, const float* __restrict__ p2,
        int H, int W, int tx, int ty, int level,
        const float* __restrict__ window,
        float* __restrict__ accum,
        float* __restrict__ pp1, float* __restrict__ pp2)
{
    const int tid = threadIdx.x;

    // 1D gaussian from 2D window: g[k] = w2[5][k]/sqrt(w2[5][5])
    float g[11];
    {
        float invg5 = 1.0f / sqrtf(window[60]);
        #pragma unroll
        for (int k = 0; k < 11; ++k) g[k] = window[55 + k] * invg5;
    }

    // ---- Phase 1: stage halo tile (42 rows x 28 cols), split images ----
    for (int s = tid; s < HR * 14; s += 256) {
        int r = s / 14, j = s - r * 14;
        int gy = ty + r - 5;
        int gx = tx - 6 + 2 * j;
        float2 v1 = make_float2(0.f, 0.f), v2 = make_float2(0.f, 0.f);
        if ((unsigned)gy < (unsigned)H && (unsigned)gx < (unsigned)W) {
            size_t o = (size_t)gy * W + gx;
            v1 = *(const float2*)(p1 + o);
            v2 = *(const float2*)(p2 + o);
        }
        sm->s1[r][2 * j]     = v1.x;
        sm->s1[r][2 * j + 1] = v1.y;
        sm->s2[r][2 * j]     = v2.x;
        sm->s2[r][2 * j + 1] = v2.y;
    }
    __syncthreads();

    // ---- Fused 2x2 avg-pool from the staged tile ----
    if (pp1 && tid < 128) {
        int pc = tid & 7;          // pooled col 0..7
        int pr = tid >> 3;         // pooled row 0..15
        int r  = 2 * pr + 5;
        int jj = 2 * pc + 6;
        float pa = 0.25f * ((sm->s1[r][jj] + sm->s1[r][jj + 1]) +
                            (sm->s1[r + 1][jj] + sm->s1[r + 1][jj + 1]));
        float pb = 0.25f * ((sm->s2[r][jj] + sm->s2[r][jj + 1]) +
                            (sm->s2[r + 1][jj] + sm->s2[r + 1][jj + 1]));
        int W2 = W >> 1;
        size_t o = (size_t)((ty >> 1) + pr) * W2 + (tx >> 1) + pc;
        pp1[o] = pa;
        pp2[o] = pb;
    }

    // ---- Phase 2: horizontal 11-tap, 2 outputs per item, sliding taps ----
    for (int gi = tid; gi < HR * 8; gi += 256) {
        int r  = gi >> 3;
        int c0 = (gi & 7) << 1;
        const float* r1 = &sm->s1[r][c0 + 1];
        const float* r2 = &sm->s2[r][c0 + 1];
        float m1a = 0, m2a = 0, q11a = 0, q22a = 0, q12a = 0;
        float m1b = 0, m2b = 0, q11b = 0, q22b = 0, q12b = 0;
        #pragma unroll
        for (int k = 0; k < 12; ++k) {              // taps j = c0+1 .. c0+12
            float a = r1[k];
            float b = r2[k];
            if (k < 11) {
                float ga = g[k] * a, gb = g[k] * b;
                m1a += ga; m2a += gb;
                q11a = fmaf(ga, a, q11a);
                q22a = fmaf(gb, b, q22a);
                q12a = fmaf(ga, b, q12a);
            }
            if (k >= 1) {
                float gk = g[k - 1];
                float ga = gk * a, gb = gk * b;
                m1b += ga; m2b += gb;
                q11b = fmaf(ga, a, q11b);
                q22b = fmaf(gb, b, q22b);
                q12b = fmaf(ga, b, q12b);
            }
        }
        *(float2*)&sm->hbuf[0][r][c0] = make_float2(m1a, m1b);
        *(float2*)&sm->hbuf[1][r][c0] = make_float2(m2a, m2b);
        *(float2*)&sm->hbuf[2][r][c0] = make_float2(q11a, q11b);
        *(float2*)&sm->hbuf[3][r][c0] = make_float2(q22a, q22b);
        *(float2*)&sm->hbuf[4][r][c0] = make_float2(q12a, q12b);
    }
    __syncthreads();

    // ---- Phase 3: vertical 11-tap, 4 stacked rows per thread + epilogue ----
    float ssum = 0.f, csum = 0.f;
    if (tid < 128) {
        int c  = tid & 15;              // output col 0..15
        int r0 = (tid >> 4) << 2;       // output rows r0..r0+3
        float M1[4]  = {0, 0, 0, 0}, M2[4]  = {0, 0, 0, 0};
        float Q11[4] = {0, 0, 0, 0}, Q22[4] = {0, 0, 0, 0}, Q12[4] = {0, 0, 0, 0};
        #pragma unroll
        for (int k = 0; k < 14; ++k) {
            float h0 = sm->hbuf[0][r0 + k][c];
            float h1 = sm->hbuf[1][r0 + k][c];
            float h2 = sm->hbuf[2][r0 + k][c];
            float h3 = sm->hbuf[3][r0 + k][c];
            float h4 = sm->hbuf[4][r0 + k][c];
            #pragma unroll
            for (int j = 0; j < 4; ++j) {
                int t = k - j;
                if (t >= 0 && t < 11) {
                    float gk = g[t];
                    M1[j]  = fmaf(gk, h0, M1[j]);
                    M2[j]  = fmaf(gk, h1, M2[j]);
                    Q11[j] = fmaf(gk, h2, Q11[j]);
                    Q22[j] = fmaf(gk, h3, Q22[j]);
                    Q12[j] = fmaf(gk, h4, Q12[j]);
                }
            }
        }
        #pragma unroll
        for (int j = 0; j < 4; ++j) {
            float mu1 = M1[j], mu2 = M2[j];
            float mu1s = mu1 * mu1, mu2s = mu2 * mu2, mu12 = mu1 * mu2;
            float v1 = Q11[j] - mu1s, v2 = Q22[j] - mu2s, v12 = Q12[j] - mu12;
            float n1 = 2.f * mu12 + SC1, n2 = 2.f * v12 + SC2;
            float d1 = mu1s + mu2s + SC1, d2 = v1 + v2 + SC2;
            float inv = 1.f / (d1 * d2);
            csum += n2 * d1 * inv;
            ssum += n1 * n2 * inv;
        }
    }

    // ---- Block reduction -> one atomic pair per block ----
    #pragma unroll
    for (int off = 32; off; off >>= 1) {
        ssum += __shfl_down(ssum, off);
        csum += __shfl_down(csum, off);
    }
    const int wid = tid >> 6, lane = tid & 63;
    if (lane == 0) { sm->rbuf[wid * 2] = ssum; sm->rbuf[wid * 2 + 1] = csum; }
    __syncthreads();
    if (tid == 0) {
        float S = sm->rbuf[0] + sm->rbuf[2] + sm->rbuf[4] + sm->rbuf[6];
        float C = sm->rbuf[1] + sm->rbuf[3] + sm->rbuf[5] + sm->rbuf[7];
        int slot = (blockIdx.x + blockIdx.y * 7 + blockIdx.z * 13) & (NSLOT - 1);
        atomicAdd(&accum[(2 * level) * NSLOT + slot], S);
        atomicAdd(&accum[(2 * level + 1) * NSLOT + slot], C);
    }
}

// ---------------- level 0 (fuses pool -> l1) -------------------------------
__global__ __launch_bounds__(256, 6) void ssim_l0(
        const float* __restrict__ img1, const float* __restrict__ img2,
        const float* __restrict__ window, float* __restrict__ accum,
        float* __restrict__ l1a, float* __restrict__ l1b)
{
    __shared__ SmemT sm;
    const int plane = blockIdx.z;
    const float* p1 = img1 + (size_t)plane * 512 * 512;
    const float* p2 = img2 + (size_t)plane * 512 * 512;
    float* pp1 = l1a + (size_t)plane * 256 * 256;
    float* pp2 = l1b + (size_t)plane * 256 * 256;
    ssim_tile(&sm, p1, p2, 512, 512, blockIdx.x * TW, blockIdx.y * TH, 0,
              window, accum, pp1, pp2);
}

// ---------------- pyramid chain: l1 -> l2, l3, l4 --------------------------
__global__ __launch_bounds__(256) void down_chain(
        const float* __restrict__ l1a, const float* __restrict__ l1b,
        float* __restrict__ l2a, float* __restrict__ l2b,
        float* __restrict__ l3a, float* __restrict__ l3b,
        float* __restrict__ l4a, float* __restrict__ l4b)
{
    __shared__ float t2[2][16][17];
    __shared__ float t3[2][8][9];
    const int plane = blockIdx.z;
    const int bx = blockIdx.x & 7, by = blockIdx.x >> 3;   // 8x8 blocks/plane
    const float* A = l1a + (size_t)plane * 256 * 256;
    const float* B = l1b + (size_t)plane * 256 * 256;
    const int tid = threadIdx.x;
    const int px = tid & 15, py = tid >> 4;                // l2 coords in block
    const int gx = bx * 32 + 2 * px, gy = by * 32 + 2 * py;
    float2 a0 = *(const float2*)(A + (size_t)gy * 256 + gx);
    float2 a1 = *(const float2*)(A + (size_t)(gy + 1) * 256 + gx);
    float2 b0 = *(const float2*)(B + (size_t)gy * 256 + gx);
    float2 b1 = *(const float2*)(B + (size_t)(gy + 1) * 256 + gx);
    float va = 0.25f * ((a0.x + a0.y) + (a1.x + a1.y));
    float vb = 0.25f * ((b0.x + b0.y) + (b1.x + b1.y));
    size_t o2 = ((size_t)plane * 128 + by * 16 + py) * 128 + bx * 16 + px;
    l2a[o2] = va; l2b[o2] = vb;
    t2[0][py][px] = va; t2[1][py][px] = vb;
    __syncthreads();
    if (tid < 64) {
        int qx = tid & 7, qy = tid >> 3;
        float sa = 0.25f * (t2[0][2*qy][2*qx] + t2[0][2*qy][2*qx+1] + t2[0][2*qy+1][2*qx] + t2[0][2*qy+1][2*qx+1]);
        float sb = 0.25f * (t2[1][2*qy][2*qx] + t2[1][2*qy][2*qx+1] + t2[1][2*qy+1][2*qx] + t2[1][2*qy+1][2*qx+1]);
        size_t o3 = ((size_t)plane * 64 + by * 8 + qy) * 64 + bx * 8 + qx;
        l3a[o3] = sa; l3b[o3] = sb;
        t3[0][qy][qx] = sa; t3[1][qy][qx] = sb;
    }
    __syncthreads();
    if (tid < 16) {
        int qx = tid & 3, qy = tid >> 2;
        float sa = 0.25f * (t3[0][2*qy][2*qx] + t3[0][2*qy][2*qx+1] + t3[0][2*qy+1][2*qx] + t3[0][2*qy+1][2*qx+1]);
        float sb = 0.25f * (t3[1][2*qy][2*qx] + t3[1][2*qy][2*qx+1] + t3[1][2*qy+1][2*qx] + t3[1][2*qy+1][2*qx+1]);
        size_t o4 = ((size_t)plane * 32 + by * 4 + qy) * 32 + bx * 4 + qx;
        l4a[o4] = sa; l4b[o4] = sb;
    }
}

// ---------------- combined levels 1-4 (one dispatch) -----------------------
__global__ __launch_bounds__(256, 6) void ssim_rest(
        const float* __restrict__ l1a, const float* __restrict__ l1b,
        const float* __restrict__ l2a, const float* __restrict__ l2b,
        const float* __restrict__ l3a, const float* __restrict__ l3b,
        const float* __restrict__ l4a, const float* __restrict__ l4b,
        const float* __restrict__ window, float* __restrict__ accum)
{
    __shared__ SmemT sm;
    const int x = blockIdx.x;        // 0..169 tile id within plane
    const int plane = blockIdx.z;
    int level, H, tix, tiy;
    const float *b1, *b2;
    if (x < 128)      { level = 1; H = 256; tix = x & 15;            tiy = x >> 4;        b1 = l1a; b2 = l1b; }
    else if (x < 160) { level = 2; H = 128; int i = x - 128; tix = i & 7; tiy = i >> 3;   b1 = l2a; b2 = l2b; }
    else if (x < 168) { level = 3; H = 64;  int i = x - 160; tix = i & 3; tiy = i >> 2;   b1 = l3a; b2 = l3b; }
    else              { level = 4; H = 32;  int i = x - 168; tix = i & 1; tiy = i >> 1;   b1 = l4a; b2 = l4b; }
    const float* p1 = b1 + (size_t)plane * H * H;
    const float* p2 = b2 + (size_t)plane * H * H;
    ssim_tile(&sm, p1, p2, H, H, tix * TW, tiy * TH, level,
              window, accum, nullptr, nullptr);
}

// ---------------- final weighted product ----------------------------------
__global__ void finalize_kernel(const float* __restrict__ accum, float* __restrict__ out) {
    int t = threadIdx.x;   // 64 threads
    float sums[10];
    #pragma unroll
    for (int i = 0; i < 10; ++i) {
        float v = accum[i * NSLOT + t];
        #pragma unroll
        for (int off = 32; off; off >>= 1) v += __shfl_down(v, off);
        sums[i] = v;
    }
    if (t == 0) {
        const float w[5] = {0.0448f, 0.2856f, 0.3001f, 0.2363f, 0.1333f};
        float res = 1.f;
        #pragma unroll
        for (int L = 0; L < 4; ++L) {
            float dim = (float)(512 >> L);
            float cnt = (float)PLANES * dim * dim;
            res *= powf(sums[2 * L + 1] / cnt, w[L]);   // cs mean, levels 0..3
        }
        float cnt4 = (float)PLANES * 32.f * 32.f;
        res *= powf(sums[8] / cnt4, w[4]);              // ssim mean, level 4
        out[0] = res;
    }
}

// ---------------- launch ---------------------------------------------------
extern "C" void kernel_launch(void* const* d_in, const int* in_sizes, int n_in,
                              void* d_out, int out_size, void* d_ws, size_t ws_size,
                              hipStream_t stream) {
    const float* img1   = (const float*)d_in[0];
    const float* img2   = (const float*)d_in[1];
    const float* window = (const float*)d_in[2];
    float* out = (float*)d_out;
    float* ws  = (float*)d_ws;

    float* accum = ws;   // 640 floats
    const size_t S1 = (size_t)PLANES * 256 * 256;
    const size_t S2 = (size_t)PLANES * 128 * 128;
    const size_t S3 = (size_t)PLANES * 64 * 64;
    const size_t S4 = (size_t)PLANES * 32 * 32;
    float* l1a = ws + 1024;    float* l1b = l1a + S1;
    float* l2a = l1b + S1;     float* l2b = l2a + S2;
    float* l3a = l2b + S2;     float* l3b = l3a + S3;
    float* l4a = l3b + S3;     float* l4b = l4a + S4;

    hipMemsetAsync(accum, 0, 10 * NSLOT * sizeof(float), stream);

    ssim_l0<<<dim3(512 / TW, 512 / TH, PLANES), 256, 0, stream>>>(
        img1, img2, window, accum, l1a, l1b);

    down_chain<<<dim3(64, 1, PLANES), 256, 0, stream>>>(
        l1a, l1b, l2a, l2b, l3a, l3b, l4a, l4b);

    ssim_rest<<<dim3(170, 1, PLANES), 256, 0, stream>>>(
        l1a, l1b, l2a, l2b, l3a, l3b, l4a, l4b, window, accum);

    finalize_kernel<<<1, 64, 0, stream>>>(accum, out);
}

// Round 6
// 315.441 us; speedup vs baseline: 1.2167x; 1.2167x over previous
//
#include <hip/hip_runtime.h>
#include <math.h>

#define TW 16                // tile width  (output cols)
#define TH 32                // tile height (output rows)
#define HR (TH + 10)         // 42 halo rows
#define SSTRIDE 29           // s1/s2 row stride: ODD -> conflict-reduced b32 (verified r5)
#define HSTRIDE 20           // hbuf col stride
#define SC1 0.0001f
#define SC2 0.0009f
#define PLANES 48
#define NSLOT 64

struct SmemT {
    float s1[HR][SSTRIDE];       // 4872 B
    float s2[HR][SSTRIDE];       // 4872 B
    float hbuf[5][HR][HSTRIDE];  // 16800 B
    float pbuf[2][16][9];        // 1152 B  l1 pool values (per-tile 16 rows x 8 cols)
    float rbuf[8];
};                               // ~27.7 KB -> 5 blocks/CU at launch_bounds(256,5)

// ---------------- core: one 16x32 SSIM tile -------------------------------
// NOTE: __launch_bounds__(256,5) everywhere. min-waves=6 forces VGPR 48->40
// and spills to scratch (WRITE_SIZE 62->296 MB, measured rounds 3 AND 5).
__device__ __forceinline__ void ssim_tile(
        SmemT* sm,
        const float* __restrict__ p1, const float* __restrict__ p2,
        int H, int W, int tx, int ty, int level,
        const float* __restrict__ window,
        float* __restrict__ accum,
        float* __restrict__ l1a, float* __restrict__ l1b,   // plane-offset level-1 out (or null)
        float* __restrict__ l2a, float* __restrict__ l2b,   // plane-offset level-2 out
        float* __restrict__ l3a, float* __restrict__ l3b,
        float* __restrict__ l4a, float* __restrict__ l4b)
{
    const int tid = threadIdx.x;

    // 1D gaussian from 2D window: g[k] = w2[5][k]/sqrt(w2[5][5])
    float g[11];
    {
        float invg5 = 1.0f / sqrtf(window[60]);
        #pragma unroll
        for (int k = 0; k < 11; ++k) g[k] = window[55 + k] * invg5;
    }

    // ---- Phase 1: stage halo tile (42 rows x 28 cols), split images ----
    for (int s = tid; s < HR * 14; s += 256) {
        int r = s / 14, j = s - r * 14;
        int gy = ty + r - 5;
        int gx = tx - 6 + 2 * j;
        float2 v1 = make_float2(0.f, 0.f), v2 = make_float2(0.f, 0.f);
        if ((unsigned)gy < (unsigned)H && (unsigned)gx < (unsigned)W) {
            size_t o = (size_t)gy * W + gx;
            v1 = *(const float2*)(p1 + o);
            v2 = *(const float2*)(p2 + o);
        }
        sm->s1[r][2 * j]     = v1.x;
        sm->s1[r][2 * j + 1] = v1.y;
        sm->s2[r][2 * j]     = v2.x;
        sm->s2[r][2 * j + 1] = v2.y;
    }
    __syncthreads();

    // ---- Fused 2x2 avg-pool -> l1 (also parked in pbuf for l2/l3/l4) ----
    if (l1a && tid < 128) {
        int pc = tid & 7;          // pooled col 0..7
        int pr = tid >> 3;         // pooled row 0..15
        int r  = 2 * pr + 5;
        int jj = 2 * pc + 6;
        float pa = 0.25f * ((sm->s1[r][jj] + sm->s1[r][jj + 1]) +
                            (sm->s1[r + 1][jj] + sm->s1[r + 1][jj + 1]));
        float pb = 0.25f * ((sm->s2[r][jj] + sm->s2[r][jj + 1]) +
                            (sm->s2[r + 1][jj] + sm->s2[r + 1][jj + 1]));
        int W2 = W >> 1;
        size_t o = (size_t)((ty >> 1) + pr) * W2 + (tx >> 1) + pc;
        l1a[o] = pa;
        l1b[o] = pb;
        sm->pbuf[0][pr][pc] = pa;
        sm->pbuf[1][pr][pc] = pb;
    }

    // ---- Phase 2: horizontal 11-tap, 2 outputs per item, sliding taps ----
    for (int gi = tid; gi < HR * 8; gi += 256) {
        int r  = gi >> 3;
        int c0 = (gi & 7) << 1;
        const float* r1 = &sm->s1[r][c0 + 1];
        const float* r2 = &sm->s2[r][c0 + 1];
        float m1a = 0, m2a = 0, q11a = 0, q22a = 0, q12a = 0;
        float m1b = 0, m2b = 0, q11b = 0, q22b = 0, q12b = 0;
        #pragma unroll
        for (int k = 0; k < 12; ++k) {              // taps j = c0+1 .. c0+12
            float a = r1[k];
            float b = r2[k];
            if (k < 11) {
                float ga = g[k] * a, gb = g[k] * b;
                m1a += ga; m2a += gb;
                q11a = fmaf(ga, a, q11a);
                q22a = fmaf(gb, b, q22a);
                q12a = fmaf(ga, b, q12a);
            }
            if (k >= 1) {
                float gk = g[k - 1];
                float ga = gk * a, gb = gk * b;
                m1b += ga; m2b += gb;
                q11b = fmaf(ga, a, q11b);
                q22b = fmaf(gb, b, q22b);
                q12b = fmaf(ga, b, q12b);
            }
        }
        *(float2*)&sm->hbuf[0][r][c0] = make_float2(m1a, m1b);
        *(float2*)&sm->hbuf[1][r][c0] = make_float2(m2a, m2b);
        *(float2*)&sm->hbuf[2][r][c0] = make_float2(q11a, q11b);
        *(float2*)&sm->hbuf[3][r][c0] = make_float2(q22a, q22b);
        *(float2*)&sm->hbuf[4][r][c0] = make_float2(q12a, q12b);
    }
    __syncthreads();

    // ---- Phase 3 (tid<128) + pyramid l2/l3/l4 on wave 2 (tid 128..191) ----
    float ssum = 0.f, csum = 0.f;
    if (tid < 128) {
        int c  = tid & 15;              // output col 0..15
        int r0 = (tid >> 4) << 2;       // output rows r0..r0+3
        float M1[4]  = {0, 0, 0, 0}, M2[4]  = {0, 0, 0, 0};
        float Q11[4] = {0, 0, 0, 0}, Q22[4] = {0, 0, 0, 0}, Q12[4] = {0, 0, 0, 0};
        #pragma unroll
        for (int k = 0; k < 14; ++k) {
            float h0 = sm->hbuf[0][r0 + k][c];
            float h1 = sm->hbuf[1][r0 + k][c];
            float h2 = sm->hbuf[2][r0 + k][c];
            float h3 = sm->hbuf[3][r0 + k][c];
            float h4 = sm->hbuf[4][r0 + k][c];
            #pragma unroll
            for (int j = 0; j < 4; ++j) {
                int t = k - j;
                if (t >= 0 && t < 11) {
                    float gk = g[t];
                    M1[j]  = fmaf(gk, h0, M1[j]);
                    M2[j]  = fmaf(gk, h1, M2[j]);
                    Q11[j] = fmaf(gk, h2, Q11[j]);
                    Q22[j] = fmaf(gk, h3, Q22[j]);
                    Q12[j] = fmaf(gk, h4, Q12[j]);
                }
            }
        }
        #pragma unroll
        for (int j = 0; j < 4; ++j) {
            float mu1 = M1[j], mu2 = M2[j];
            float mu1s = mu1 * mu1, mu2s = mu2 * mu2, mu12 = mu1 * mu2;
            float v1 = Q11[j] - mu1s, v2 = Q22[j] - mu2s, v12 = Q12[j] - mu12;
            float n1 = 2.f * mu12 + SC1, n2 = 2.f * v12 + SC2;
            float d1 = mu1s + mu2s + SC1, d2 = v1 + v2 + SC2;
            float inv = 1.f / (d1 * d2);
            csum += n2 * d1 * inv;
            ssum += n1 * n2 * inv;
        }
    } else if (l1a && tid < 192) {
        // Wave 2: derive l2 (4x8), l3 (2x4), l4 (1x2) for this tile.
        const int lane = tid - 128;
        // l2: lanes 0..31, qr=0..7, qc=0..3
        float v2a = 0.f, v2b = 0.f;
        {
            int qc = lane & 3, qr = lane >> 2;          // valid for lane<32
            int rr = (qr & 7) * 2, cc = (qc & 3) * 2;
            v2a = 0.25f * ((sm->pbuf[0][rr][cc] + sm->pbuf[0][rr][cc + 1]) +
                           (sm->pbuf[0][rr + 1][cc] + sm->pbuf[0][rr + 1][cc + 1]));
            v2b = 0.25f * ((sm->pbuf[1][rr][cc] + sm->pbuf[1][rr][cc + 1]) +
                           (sm->pbuf[1][rr + 1][cc] + sm->pbuf[1][rr + 1][cc + 1]));
            if (lane < 32) {
                int W4 = W >> 2;
                size_t o = (size_t)((ty >> 2) + qr) * W4 + (tx >> 2) + qc;
                l2a[o] = v2a;
                l2b[o] = v2b;
            }
        }
        // l3: lanes 0..7, tr=lane>>1 (0..3), tc=lane&1
        float v3a, v3b;
        {
            int tr = (lane >> 1) & 3, tc = lane & 1;
            int l00 = 8 * tr + 2 * tc;                  // l2 lane of (2tr,2tc)
            v3a = 0.25f * (__shfl(v2a, l00) + __shfl(v2a, l00 + 1) +
                           __shfl(v2a, l00 + 4) + __shfl(v2a, l00 + 5));
            v3b = 0.25f * (__shfl(v2b, l00) + __shfl(v2b, l00 + 1) +
                           __shfl(v2b, l00 + 4) + __shfl(v2b, l00 + 5));
            if (lane < 8) {
                int W8 = W >> 3;
                size_t o = (size_t)((ty >> 3) + tr) * W8 + (tx >> 3) + tc;
                l3a[o] = v3a;
                l3b[o] = v3b;
            }
        }
        // l4: lanes 0..1, ur=lane
        {
            int ur = lane & 1;
            float v4a = 0.25f * (__shfl(v3a, 4 * ur) + __shfl(v3a, 4 * ur + 1) +
                                 __shfl(v3a, 4 * ur + 2) + __shfl(v3a, 4 * ur + 3));
            float v4b = 0.25f * (__shfl(v3b, 4 * ur) + __shfl(v3b, 4 * ur + 1) +
                                 __shfl(v3b, 4 * ur + 2) + __shfl(v3b, 4 * ur + 3));
            if (lane < 2) {
                int W16 = W >> 4;
                size_t o = (size_t)((ty >> 4) + ur) * W16 + (tx >> 4);
                l4a[o] = v4a;
                l4b[o] = v4b;
            }
        }
    }

    // ---- Block reduction -> one atomic pair per block ----
    #pragma unroll
    for (int off = 32; off; off >>= 1) {
        ssum += __shfl_down(ssum, off);
        csum += __shfl_down(csum, off);
    }
    const int wid = tid >> 6, lane = tid & 63;
    if (lane == 0) { sm->rbuf[wid * 2] = ssum; sm->rbuf[wid * 2 + 1] = csum; }
    __syncthreads();
    if (tid == 0) {
        float S = sm->rbuf[0] + sm->rbuf[2] + sm->rbuf[4] + sm->rbuf[6];
        float C = sm->rbuf[1] + sm->rbuf[3] + sm->rbuf[5] + sm->rbuf[7];
        int slot = (blockIdx.x + blockIdx.y * 7 + blockIdx.z * 13) & (NSLOT - 1);
        atomicAdd(&accum[(2 * level) * NSLOT + slot], S);
        atomicAdd(&accum[(2 * level + 1) * NSLOT + slot], C);
    }
}

// ---------------- level 0: SSIM + full pyramid -----------------------------
__global__ __launch_bounds__(256, 5) void ssim_l0(
        const float* __restrict__ img1, const float* __restrict__ img2,
        const float* __restrict__ window, float* __restrict__ accum,
        float* __restrict__ l1a, float* __restrict__ l1b,
        float* __restrict__ l2a, float* __restrict__ l2b,
        float* __restrict__ l3a, float* __restrict__ l3b,
        float* __restrict__ l4a, float* __restrict__ l4b)
{
    __shared__ SmemT sm;
    const int plane = blockIdx.z;
    ssim_tile(&sm,
              img1 + (size_t)plane * 512 * 512,
              img2 + (size_t)plane * 512 * 512,
              512, 512, blockIdx.x * TW, blockIdx.y * TH, 0,
              window, accum,
              l1a + (size_t)plane * 256 * 256, l1b + (size_t)plane * 256 * 256,
              l2a + (size_t)plane * 128 * 128, l2b + (size_t)plane * 128 * 128,
              l3a + (size_t)plane * 64 * 64,   l3b + (size_t)plane * 64 * 64,
              l4a + (size_t)plane * 32 * 32,   l4b + (size_t)plane * 32 * 32);
}

// ---------------- combined levels 1-4 (one dispatch) -----------------------
__global__ __launch_bounds__(256, 5) void ssim_rest(
        const float* __restrict__ l1a, const float* __restrict__ l1b,
        const float* __restrict__ l2a, const float* __restrict__ l2b,
        const float* __restrict__ l3a, const float* __restrict__ l3b,
        const float* __restrict__ l4a, const float* __restrict__ l4b,
        const float* __restrict__ window, float* __restrict__ accum)
{
    __shared__ SmemT sm;
    const int x = blockIdx.x;        // 0..169 tile id within plane
    const int plane = blockIdx.z;
    int level, H, tix, tiy;
    const float *b1, *b2;
    if (x < 128)      { level = 1; H = 256; tix = x & 15;            tiy = x >> 4;        b1 = l1a; b2 = l1b; }
    else if (x < 160) { level = 2; H = 128; int i = x - 128; tix = i & 7; tiy = i >> 3;   b1 = l2a; b2 = l2b; }
    else if (x < 168) { level = 3; H = 64;  int i = x - 160; tix = i & 3; tiy = i >> 2;   b1 = l3a; b2 = l3b; }
    else              { level = 4; H = 32;  int i = x - 168; tix = i & 1; tiy = i >> 1;   b1 = l4a; b2 = l4b; }
    const float* p1 = b1 + (size_t)plane * H * H;
    const float* p2 = b2 + (size_t)plane * H * H;
    ssim_tile(&sm, p1, p2, H, H, tix * TW, tiy * TH, level,
              window, accum,
              nullptr, nullptr, nullptr, nullptr,
              nullptr, nullptr, nullptr, nullptr);
}

// ---------------- final weighted product ----------------------------------
__global__ void finalize_kernel(const float* __restrict__ accum, float* __restrict__ out) {
    int t = threadIdx.x;   // 64 threads
    float sums[10];
    #pragma unroll
    for (int i = 0; i < 10; ++i) {
        float v = accum[i * NSLOT + t];
        #pragma unroll
        for (int off = 32; off; off >>= 1) v += __shfl_down(v, off);
        sums[i] = v;
    }
    if (t == 0) {
        const float w[5] = {0.0448f, 0.2856f, 0.3001f, 0.2363f, 0.1333f};
        float res = 1.f;
        #pragma unroll
        for (int L = 0; L < 4; ++L) {
            float dim = (float)(512 >> L);
            float cnt = (float)PLANES * dim * dim;
            res *= powf(sums[2 * L + 1] / cnt, w[L]);   // cs mean, levels 0..3
        }
        float cnt4 = (float)PLANES * 32.f * 32.f;
        res *= powf(sums[8] / cnt4, w[4]);              // ssim mean, level 4
        out[0] = res;
    }
}

// ---------------- launch ---------------------------------------------------
extern "C" void kernel_launch(void* const* d_in, const int* in_sizes, int n_in,
                              void* d_out, int out_size, void* d_ws, size_t ws_size,
                              hipStream_t stream) {
    const float* img1   = (const float*)d_in[0];
    const float* img2   = (const float*)d_in[1];
    const float* window = (const float*)d_in[2];
    float* out = (float*)d_out;
    float* ws  = (float*)d_ws;

    float* accum = ws;   // 640 floats
    const size_t S1 = (size_t)PLANES * 256 * 256;
    const size_t S2 = (size_t)PLANES * 128 * 128;
    const size_t S3 = (size_t)PLANES * 64 * 64;
    const size_t S4 = (size_t)PLANES * 32 * 32;
    float* l1a = ws + 1024;    float* l1b = l1a + S1;
    float* l2a = l1b + S1;     float* l2b = l2a + S2;
    float* l3a = l2b + S2;     float* l3b = l3a + S3;
    float* l4a = l3b + S3;     float* l4b = l4a + S4;

    hipMemsetAsync(accum, 0, 10 * NSLOT * sizeof(float), stream);

    ssim_l0<<<dim3(512 / TW, 512 / TH, PLANES), 256, 0, stream>>>(
        img1, img2, window, accum,
        l1a, l1b, l2a, l2b, l3a, l3b, l4a, l4b);

    ssim_rest<<<dim3(170, 1, PLANES), 256, 0, stream>>>(
        l1a, l1b, l2a, l2b, l3a, l3b, l4a, l4b, window, accum);

    finalize_kernel<<<1, 64, 0, stream>>>(accum, out);
}

// Round 7
// 304.850 us; speedup vs baseline: 1.2590x; 1.0347x over previous
//
#include <hip/hip_runtime.h>
#include <math.h>

#define TW 16                // tile width  (output cols)
#define TH 32                // tile height (output rows)
#define HR (TH + 10)         // 42 halo rows
#define SSTRIDE 29           // s1/s2 row stride: ODD -> conflict-reduced b32 (verified r5)
#define HSTRIDE 20           // hbuf col stride: 40*rg mod 32 = {0,8,16,24} -> phase-3 2-way (free)
#define SC1 0.0001f
#define SC2 0.0009f
#define PLANES 48
#define NSLOT 64

struct SmemT {
    float s1[HR][SSTRIDE];       // 4872 B
    float s2[HR][SSTRIDE];       // 4872 B
    float hbuf[5][HR][HSTRIDE];  // 16800 B
    float rbuf[8];
};                               // 26576 B -> 6 blocks/CU (159.7 KB of 160)

// ---------------- core: one 16x32 SSIM tile -------------------------------
// NOTE: __launch_bounds__(256,5). min-waves=6 forces VGPR 48->40 and spills
// to scratch (WRITE_SIZE 62->296 MB, measured rounds 3 AND 5). Occupancy of
// 6 blocks/CU comes from LDS fit, not from the launch_bounds arg.
__device__ __forceinline__ void ssim_tile(
        SmemT* sm,
        const float* __restrict__ p1, const float* __restrict__ p2,
        int H, int W, int tx, int ty, int level,
        const float* __restrict__ window,
        float* __restrict__ accum,
        float* __restrict__ l1a, float* __restrict__ l1b,   // plane-offset outs (or null)
        float* __restrict__ l2a, float* __restrict__ l2b,
        float* __restrict__ l3a, float* __restrict__ l3b,
        float* __restrict__ l4a, float* __restrict__ l4b)
{
    const int tid = threadIdx.x;

    // 1D gaussian from 2D window: g[k] = w2[5][k]/sqrt(w2[5][5])
    float g[11];
    {
        float invg5 = 1.0f / sqrtf(window[60]);
        #pragma unroll
        for (int k = 0; k < 11; ++k) g[k] = window[55 + k] * invg5;
    }

    // ---- Phase 1: stage halo tile (42 rows x 28 cols), split images ----
    for (int s = tid; s < HR * 14; s += 256) {
        int r = s / 14, j = s - r * 14;
        int gy = ty + r - 5;
        int gx = tx - 6 + 2 * j;
        float2 v1 = make_float2(0.f, 0.f), v2 = make_float2(0.f, 0.f);
        if ((unsigned)gy < (unsigned)H && (unsigned)gx < (unsigned)W) {
            size_t o = (size_t)gy * W + gx;
            v1 = *(const float2*)(p1 + o);
            v2 = *(const float2*)(p2 + o);
        }
        sm->s1[r][2 * j]     = v1.x;
        sm->s1[r][2 * j + 1] = v1.y;
        sm->s2[r][2 * j]     = v2.x;
        sm->s2[r][2 * j + 1] = v2.y;
    }
    __syncthreads();

    // ---- Fused 2x2 avg-pool -> l1 (from staged tile) ----
    if (l1a && tid < 128) {
        int pc = tid & 7;          // pooled col 0..7
        int pr = tid >> 3;         // pooled row 0..15
        int r  = 2 * pr + 5;
        int jj = 2 * pc + 6;
        float pa = 0.25f * ((sm->s1[r][jj] + sm->s1[r][jj + 1]) +
                            (sm->s1[r + 1][jj] + sm->s1[r + 1][jj + 1]));
        float pb = 0.25f * ((sm->s2[r][jj] + sm->s2[r][jj + 1]) +
                            (sm->s2[r + 1][jj] + sm->s2[r + 1][jj + 1]));
        int W2 = W >> 1;
        size_t o = (size_t)((ty >> 1) + pr) * W2 + (tx >> 1) + pc;
        l1a[o] = pa;
        l1b[o] = pb;
    }

    // ---- Phase 2: horizontal 11-tap, 2 outputs per item, sliding taps ----
    for (int gi = tid; gi < HR * 8; gi += 256) {
        int r  = gi >> 3;
        int c0 = (gi & 7) << 1;
        const float* r1 = &sm->s1[r][c0 + 1];
        const float* r2 = &sm->s2[r][c0 + 1];
        float m1a = 0, m2a = 0, q11a = 0, q22a = 0, q12a = 0;
        float m1b = 0, m2b = 0, q11b = 0, q22b = 0, q12b = 0;
        #pragma unroll
        for (int k = 0; k < 12; ++k) {              // taps j = c0+1 .. c0+12
            float a = r1[k];
            float b = r2[k];
            if (k < 11) {
                float ga = g[k] * a, gb = g[k] * b;
                m1a += ga; m2a += gb;
                q11a = fmaf(ga, a, q11a);
                q22a = fmaf(gb, b, q22a);
                q12a = fmaf(ga, b, q12a);
            }
            if (k >= 1) {
                float gk = g[k - 1];
                float ga = gk * a, gb = gk * b;
                m1b += ga; m2b += gb;
                q11b = fmaf(ga, a, q11b);
                q22b = fmaf(gb, b, q22b);
                q12b = fmaf(ga, b, q12b);
            }
        }
        *(float2*)&sm->hbuf[0][r][c0] = make_float2(m1a, m1b);
        *(float2*)&sm->hbuf[1][r][c0] = make_float2(m2a, m2b);
        *(float2*)&sm->hbuf[2][r][c0] = make_float2(q11a, q11b);
        *(float2*)&sm->hbuf[3][r][c0] = make_float2(q22a, q22b);
        *(float2*)&sm->hbuf[4][r][c0] = make_float2(q12a, q12b);
    }
    __syncthreads();

    // ---- Phase 3: vertical 11-tap, ALL 256 threads, 2 stacked rows each ----
    float ssum = 0.f, csum = 0.f;
    {
        const int c  = tid & 15;              // output col 0..15
        const int r0 = (tid >> 4) << 1;       // output rows r0, r0+1
        float M1[2]  = {0, 0}, M2[2]  = {0, 0};
        float Q11[2] = {0, 0}, Q22[2] = {0, 0}, Q12[2] = {0, 0};
        #pragma unroll
        for (int k = 0; k < 12; ++k) {        // h-rows r0+k; j uses t=k-j in [0,10]
            float h0 = sm->hbuf[0][r0 + k][c];
            float h1 = sm->hbuf[1][r0 + k][c];
            float h2 = sm->hbuf[2][r0 + k][c];
            float h3 = sm->hbuf[3][r0 + k][c];
            float h4 = sm->hbuf[4][r0 + k][c];
            #pragma unroll
            for (int j = 0; j < 2; ++j) {
                int t = k - j;                // compile-time resolved in unrolled body
                if (t >= 0 && t < 11) {
                    float gk = g[t];
                    M1[j]  = fmaf(gk, h0, M1[j]);
                    M2[j]  = fmaf(gk, h1, M2[j]);
                    Q11[j] = fmaf(gk, h2, Q11[j]);
                    Q22[j] = fmaf(gk, h3, Q22[j]);
                    Q12[j] = fmaf(gk, h4, Q12[j]);
                }
            }
        }
        #pragma unroll
        for (int j = 0; j < 2; ++j) {
            float mu1 = M1[j], mu2 = M2[j];
            float mu1s = mu1 * mu1, mu2s = mu2 * mu2, mu12 = mu1 * mu2;
            float v1 = Q11[j] - mu1s, v2 = Q22[j] - mu2s, v12 = Q12[j] - mu12;
            float n1 = 2.f * mu12 + SC1, n2 = 2.f * v12 + SC2;
            float d1 = mu1s + mu2s + SC1, d2 = v1 + v2 + SC2;
            float inv = 1.f / (d1 * d2);
            csum += n2 * d1 * inv;
            ssum += n1 * n2 * inv;
        }
    }

    // ---- Pyramid l2/l3/l4 on wave 1 lanes 0..31 (s1/s2 still valid) ----
    if (l1a && tid >= 64 && tid < 96) {
        const int lane = tid - 64;
        // l2 px (qr,qc) = 4x4 mean of original px rows 4qr..4qr+3, cols 4qc..4qc+3
        int qr = lane >> 2, qc = lane & 3;
        int rb = 4 * qr + 5, cb = 4 * qc + 6;
        float sa = 0.f, sb = 0.f;
        #pragma unroll
        for (int i = 0; i < 4; ++i)
            #pragma unroll
            for (int j = 0; j < 4; ++j) {
                sa += sm->s1[rb + i][cb + j];
                sb += sm->s2[rb + i][cb + j];
            }
        float v2a = 0.0625f * sa, v2b = 0.0625f * sb;
        {
            int W4 = W >> 2;
            size_t o = (size_t)((ty >> 2) + qr) * W4 + (tx >> 2) + qc;
            l2a[o] = v2a;
            l2b[o] = v2b;
        }
        // l3: lanes 0..7
        float v3a, v3b;
        {
            int tr = (lane >> 1) & 3, tc = lane & 1;
            int l00 = 8 * tr + 2 * tc;
            v3a = 0.25f * (__shfl(v2a, l00) + __shfl(v2a, l00 + 1) +
                           __shfl(v2a, l00 + 4) + __shfl(v2a, l00 + 5));
            v3b = 0.25f * (__shfl(v2b, l00) + __shfl(v2b, l00 + 1) +
                           __shfl(v2b, l00 + 4) + __shfl(v2b, l00 + 5));
            if (lane < 8) {
                int W8 = W >> 3;
                size_t o = (size_t)((ty >> 3) + tr) * W8 + (tx >> 3) + tc;
                l3a[o] = v3a;
                l3b[o] = v3b;
            }
        }
        // l4: lanes 0..1
        {
            int ur = lane & 1;
            float v4a = 0.25f * (__shfl(v3a, 4 * ur) + __shfl(v3a, 4 * ur + 1) +
                                 __shfl(v3a, 4 * ur + 2) + __shfl(v3a, 4 * ur + 3));
            float v4b = 0.25f * (__shfl(v3b, 4 * ur) + __shfl(v3b, 4 * ur + 1) +
                                 __shfl(v3b, 4 * ur + 2) + __shfl(v3b, 4 * ur + 3));
            if (lane < 2) {
                int W16 = W >> 4;
                size_t o = (size_t)((ty >> 4) + ur) * W16 + (tx >> 4);
                l4a[o] = v4a;
                l4b[o] = v4b;
            }
        }
    }

    // ---- Block reduction -> one atomic pair per block ----
    #pragma unroll
    for (int off = 32; off; off >>= 1) {
        ssum += __shfl_down(ssum, off);
        csum += __shfl_down(csum, off);
    }
    const int wid = tid >> 6, lane = tid & 63;
    if (lane == 0) { sm->rbuf[wid * 2] = ssum; sm->rbuf[wid * 2 + 1] = csum; }
    __syncthreads();
    if (tid == 0) {
        float S = sm->rbuf[0] + sm->rbuf[2] + sm->rbuf[4] + sm->rbuf[6];
        float C = sm->rbuf[1] + sm->rbuf[3] + sm->rbuf[5] + sm->rbuf[7];
        int slot = (blockIdx.x + blockIdx.y * 7 + blockIdx.z * 13) & (NSLOT - 1);
        atomicAdd(&accum[(2 * level) * NSLOT + slot], S);
        atomicAdd(&accum[(2 * level + 1) * NSLOT + slot], C);
    }
}

// ---------------- level 0: SSIM + full pyramid -----------------------------
__global__ __launch_bounds__(256, 5) void ssim_l0(
        const float* __restrict__ img1, const float* __restrict__ img2,
        const float* __restrict__ window, float* __restrict__ accum,
        float* __restrict__ l1a, float* __restrict__ l1b,
        float* __restrict__ l2a, float* __restrict__ l2b,
        float* __restrict__ l3a, float* __restrict__ l3b,
        float* __restrict__ l4a, float* __restrict__ l4b)
{
    __shared__ SmemT sm;
    const int plane = blockIdx.z;
    ssim_tile(&sm,
              img1 + (size_t)plane * 512 * 512,
              img2 + (size_t)plane * 512 * 512,
              512, 512, blockIdx.x * TW, blockIdx.y * TH, 0,
              window, accum,
              l1a + (size_t)plane * 256 * 256, l1b + (size_t)plane * 256 * 256,
              l2a + (size_t)plane * 128 * 128, l2b + (size_t)plane * 128 * 128,
              l3a + (size_t)plane * 64 * 64,   l3b + (size_t)plane * 64 * 64,
              l4a + (size_t)plane * 32 * 32,   l4b + (size_t)plane * 32 * 32);
}

// ---------------- combined levels 1-4 (one dispatch) -----------------------
__global__ __launch_bounds__(256, 5) void ssim_rest(
        const float* __restrict__ l1a, const float* __restrict__ l1b,
        const float* __restrict__ l2a, const float* __restrict__ l2b,
        const float* __restrict__ l3a, const float* __restrict__ l3b,
        const float* __restrict__ l4a, const float* __restrict__ l4b,
        const float* __restrict__ window, float* __restrict__ accum)
{
    __shared__ SmemT sm;
    const int x = blockIdx.x;        // 0..169 tile id within plane
    const int plane = blockIdx.z;
    int level, H, tix, tiy;
    const float *b1, *b2;
    if (x < 128)      { level = 1; H = 256; tix = x & 15;            tiy = x >> 4;        b1 = l1a; b2 = l1b; }
    else if (x < 160) { level = 2; H = 128; int i = x - 128; tix = i & 7; tiy = i >> 3;   b1 = l2a; b2 = l2b; }
    else if (x < 168) { level = 3; H = 64;  int i = x - 160; tix = i & 3; tiy = i >> 2;   b1 = l3a; b2 = l3b; }
    else              { level = 4; H = 32;  int i = x - 168; tix = i & 1; tiy = i >> 1;   b1 = l4a; b2 = l4b; }
    const float* p1 = b1 + (size_t)plane * H * H;
    const float* p2 = b2 + (size_t)plane * H * H;
    ssim_tile(&sm, p1, p2, H, H, tix * TW, tiy * TH, level,
              window, accum,
              nullptr, nullptr, nullptr, nullptr,
              nullptr, nullptr, nullptr, nullptr);
}

// ---------------- final weighted product ----------------------------------
__global__ void finalize_kernel(const float* __restrict__ accum, float* __restrict__ out) {
    int t = threadIdx.x;   // 64 threads
    float sums[10];
    #pragma unroll
    for (int i = 0; i < 10; ++i) {
        float v = accum[i * NSLOT + t];
        #pragma unroll
        for (int off = 32; off; off >>= 1) v += __shfl_down(v, off);
        sums[i] = v;
    }
    if (t == 0) {
        const float w[5] = {0.0448f, 0.2856f, 0.3001f, 0.2363f, 0.1333f};
        float res = 1.f;
        #pragma unroll
        for (int L = 0; L < 4; ++L) {
            float dim = (float)(512 >> L);
            float cnt = (float)PLANES * dim * dim;
            res *= powf(sums[2 * L + 1] / cnt, w[L]);   // cs mean, levels 0..3
        }
        float cnt4 = (float)PLANES * 32.f * 32.f;
        res *= powf(sums[8] / cnt4, w[4]);              // ssim mean, level 4
        out[0] = res;
    }
}

// ---------------- launch ---------------------------------------------------
extern "C" void kernel_launch(void* const* d_in, const int* in_sizes, int n_in,
                              void* d_out, int out_size, void* d_ws, size_t ws_size,
                              hipStream_t stream) {
    const float* img1   = (const float*)d_in[0];
    const float* img2   = (const float*)d_in[1];
    const float* window = (const float*)d_in[2];
    float* out = (float*)d_out;
    float* ws  = (float*)d_ws;

    float* accum = ws;   // 640 floats
    const size_t S1 = (size_t)PLANES * 256 * 256;
    const size_t S2 = (size_t)PLANES * 128 * 128;
    const size_t S3 = (size_t)PLANES * 64 * 64;
    const size_t S4 = (size_t)PLANES * 32 * 32;
    float* l1a = ws + 1024;    float* l1b = l1a + S1;
    float* l2a = l1b + S1;     float* l2b = l2a + S2;
    float* l3a = l2b + S2;     float* l3b = l3a + S3;
    float* l4a = l3b + S3;     float* l4b = l4a + S4;

    hipMemsetAsync(accum, 0, 10 * NSLOT * sizeof(float), stream);

    ssim_l0<<<dim3(512 / TW, 512 / TH, PLANES), 256, 0, stream>>>(
        img1, img2, window, accum,
        l1a, l1b, l2a, l2b, l3a, l3b, l4a, l4b);

    ssim_rest<<<dim3(170, 1, PLANES), 256, 0, stream>>>(
        l1a, l1b, l2a, l2b, l3a, l3b, l4a, l4b, window, accum);

    finalize_kernel<<<1, 64, 0, stream>>>(accum, out);
}